// Round 1
// baseline (584.787 us; speedup 1.0000x reference)
//
#include <hip/hip_runtime.h>
#include <math.h>

#define DEV __device__ __forceinline__

// ---- ws float layout (total < 4416 floats ~ 17.7 KB) ----
// [0..3]  : reduction slots (bits of non-negative floats): max|x|, max h1, max h2, max h3
// [16..]  : quantized weights (stored as float-valued integers) + per-row weight scales
static constexpr int W1Q = 16;            // 64*16
static constexpr int W1S = W1Q + 64 * 16; // 64
static constexpr int W2Q = W1S + 64;      // 32*64
static constexpr int W2S = W2Q + 32 * 64; // 32
static constexpr int W3Q = W2S + 32;      // 32*32
static constexpr int W3S = W3Q + 32 * 32; // 32
static constexpr int W4Q = W3S + 32;      // 5*32
static constexpr int W4S = W4Q + 5 * 32;  // 5

DEV float qact(float v, float inv) {
    // round-half-even, clip to [-32768, 32767]
    return fminf(fmaxf(rintf(v * inv), -32768.f), 32767.f);
}

DEV float qbias(float b, float bs) {
    float q = rintf(b / bs);
    return fminf(fmaxf(q, -2.147483648e9f), 2.147483648e9f);
}

DEV void reduceAndAtomicMax(float v, unsigned int* slot) {
    #pragma unroll
    for (int off = 32; off; off >>= 1) v = fmaxf(v, __shfl_xor(v, off));
    __shared__ float sm[4];
    const int wid = threadIdx.x >> 6;
    if ((threadIdx.x & 63) == 0) sm[wid] = v;
    __syncthreads();
    if (threadIdx.x == 0) {
        float m = fmaxf(fmaxf(sm[0], sm[1]), fmaxf(sm[2], sm[3]));
        atomicMax(slot, __float_as_uint(m)); // non-negative floats: bit-order == value-order
    }
}

// ---- setup: quantize weights into ws; also zero the 4 reduction slots ----
__global__ __launch_bounds__(256) void k_quantw(const float* __restrict__ W1,
                                                const float* __restrict__ W2,
                                                const float* __restrict__ W3,
                                                const float* __restrict__ W4,
                                                float* __restrict__ ws) {
    const int t = threadIdx.x;
    if (t >= 192 && t < 196) ((unsigned int*)ws)[t - 192] = 0u;

    const float* W = nullptr; int row = -1, cols = 0; float* dq = nullptr; float* dsc = nullptr;
    if (t < 64)       { W = W1; row = t;       cols = 16; dq = ws + W1Q + row * 16; dsc = ws + W1S + row; }
    else if (t < 96)  { W = W2; row = t - 64;  cols = 64; dq = ws + W2Q + row * 64; dsc = ws + W2S + row; }
    else if (t < 128) { W = W3; row = t - 96;  cols = 32; dq = ws + W3Q + row * 32; dsc = ws + W3S + row; }
    else if (t < 133) { W = W4; row = t - 128; cols = 32; dq = ws + W4Q + row * 32; dsc = ws + W4S + row; }
    if (row >= 0) {
        const float* src = W + row * cols;
        float m = 0.f;
        for (int i = 0; i < cols; i++) m = fmaxf(m, fabsf(src[i]));
        float s = fmaxf(m * (1.0f / 127.0f), 1e-8f);
        *dsc = s;
        for (int i = 0; i < cols; i++) {
            float q = rintf(src[i] / s);
            dq[i] = fminf(fmaxf(q, -128.f), 127.f);
        }
    }
}

// ---- K0: max|x| ----
__global__ __launch_bounds__(256) void k_absmax(const float4* __restrict__ x,
                                                unsigned int* __restrict__ slots, int n4) {
    float m = 0.f;
    for (int i = blockIdx.x * blockDim.x + threadIdx.x; i < n4; i += gridDim.x * blockDim.x) {
        float4 v = x[i];
        m = fmaxf(m, fmaxf(fmaxf(fabsf(v.x), fabsf(v.y)), fmaxf(fabsf(v.z), fabsf(v.w))));
    }
    reduceAndAtomicMax(m, slots + 0);
}

// ---- fused integer linear layer: out = (in_int @ Wq^T + b_int) * bias_scale ----
template <int IN, int OUT, bool RELU>
DEV void layer(const float* __restrict__ wq, const float2* __restrict__ bias,
               const float* in, float* outv) {
    #pragma unroll
    for (int o = 0; o < OUT; o++) {
        float a0 = 0.f, a1 = 0.f, a2 = 0.f, a3 = 0.f;
        const float* wr = wq + o * IN;
        #pragma unroll
        for (int i = 0; i < IN; i += 4) {
            a0 = fmaf(in[i + 0], wr[i + 0], a0);
            a1 = fmaf(in[i + 1], wr[i + 1], a1);
            a2 = fmaf(in[i + 2], wr[i + 2], a2);
            a3 = fmaf(in[i + 3], wr[i + 3], a3);
        }
        float2 bb = bias[o];
        float v = (((a0 + a1) + (a2 + a3)) + bb.x) * bb.y;
        outv[o] = RELU ? fmaxf(v, 0.f) : v;
    }
}

template <int N>
DEV void quant_arr(float* h, float inv) { // h >= 0 (post-relu)
    #pragma unroll
    for (int i = 0; i < N; i++) h[i] = fminf(rintf(h[i] * inv), 32767.f);
}

template <int N>
DEV float maxarr(const float* h) {
    float m = 0.f;
    #pragma unroll
    for (int i = 0; i < N; i++) m = fmaxf(m, h[i]);
    return m;
}

// ---- staged forward: recompute through layer STAGE; stages 1..3 reduce max, stage 4 writes out ----
template <int STAGE>
__global__ __launch_bounds__(256) void k_stage(const float* __restrict__ x,
                                               const float* __restrict__ b1,
                                               const float* __restrict__ b2,
                                               const float* __restrict__ b3,
                                               const float* __restrict__ b4,
                                               const float* __restrict__ ws,
                                               unsigned int* __restrict__ slots,
                                               float* __restrict__ out) {
    __shared__ float2 B1[64], B2[32], B3[32], B4[8];
    const int t = threadIdx.x;

    const float s0 = fmaxf(__uint_as_float(slots[0]) * (1.f / 32767.f), 1e-8f);
    float s1 = 1.f, s2 = 1.f, s3 = 1.f;
    if (STAGE >= 2) s1 = fmaxf(__uint_as_float(slots[1]) * (1.f / 32767.f), 1e-8f);
    if (STAGE >= 3) s2 = fmaxf(__uint_as_float(slots[2]) * (1.f / 32767.f), 1e-8f);
    if (STAGE >= 4) s3 = fmaxf(__uint_as_float(slots[3]) * (1.f / 32767.f), 1e-8f);

    if (t < 64) { float wsc = ws[W1S + t]; float bs = wsc * s0; B1[t] = make_float2(qbias(b1[t], bs), bs); }
    if (STAGE >= 2 && t < 32) { float wsc = ws[W2S + t]; float bs = wsc * s1; B2[t] = make_float2(qbias(b2[t], bs), bs); }
    if (STAGE >= 3 && t < 32) { float wsc = ws[W3S + t]; float bs = wsc * s2; B3[t] = make_float2(qbias(b3[t], bs), bs); }
    if (STAGE >= 4 && t < 5)  { float wsc = ws[W4S + t]; float bs = wsc * s3; B4[t] = make_float2(qbias(b4[t], bs), bs); }
    __syncthreads();

    const size_t row = (size_t)blockIdx.x * 256 + t;

    // quantize input row (16 elems)
    float xq[16];
    {
        const float4* xr = (const float4*)(x + row * 16);
        const float inv0 = 1.f / s0;
        #pragma unroll
        for (int c = 0; c < 4; c++) {
            float4 v = xr[c];
            xq[4 * c + 0] = qact(v.x, inv0);
            xq[4 * c + 1] = qact(v.y, inv0);
            xq[4 * c + 2] = qact(v.z, inv0);
            xq[4 * c + 3] = qact(v.w, inv0);
        }
    }

    float h1[64];
    layer<16, 64, true>(ws + W1Q, B1, xq, h1);
    if (STAGE == 1) { reduceAndAtomicMax(maxarr<64>(h1), slots + 1); return; }
    quant_arr<64>(h1, 1.f / s1);

    float h2[32];
    layer<64, 32, true>(ws + W2Q, B2, h1, h2);
    if (STAGE == 2) { reduceAndAtomicMax(maxarr<32>(h2), slots + 2); return; }
    quant_arr<32>(h2, 1.f / s2);

    float h3[32];
    layer<32, 32, true>(ws + W3Q, B3, h2, h3);
    if (STAGE == 3) { reduceAndAtomicMax(maxarr<32>(h3), slots + 3); return; }
    quant_arr<32>(h3, 1.f / s3);

    float lg[5];
    layer<32, 5, false>(ws + W4Q, B4, h3, lg);

    // softmax over 5
    float m = lg[0];
    #pragma unroll
    for (int i = 1; i < 5; i++) m = fmaxf(m, lg[i]);
    float e[5], ssum = 0.f;
    #pragma unroll
    for (int i = 0; i < 5; i++) { e[i] = expf(lg[i] - m); ssum += e[i]; }
    const float r = 1.f / ssum;
    #pragma unroll
    for (int i = 0; i < 5; i++) out[row * 5 + i] = e[i] * r;
}

extern "C" void kernel_launch(void* const* d_in, const int* in_sizes, int n_in,
                              void* d_out, int out_size, void* d_ws, size_t ws_size,
                              hipStream_t stream) {
    const float* x  = (const float*)d_in[0];
    const float* W1 = (const float*)d_in[1];
    const float* b1 = (const float*)d_in[2];
    const float* W2 = (const float*)d_in[3];
    const float* b2 = (const float*)d_in[4];
    const float* W3 = (const float*)d_in[5];
    const float* b3 = (const float*)d_in[6];
    const float* W4 = (const float*)d_in[7];
    const float* b4 = (const float*)d_in[8];
    float* out = (float*)d_out;
    float* ws = (float*)d_ws;
    unsigned int* slots = (unsigned int*)d_ws;

    const int B = in_sizes[0] / 16;      // 1 << 20
    const int blocks = (B + 255) / 256;  // 4096

    k_quantw<<<1, 256, 0, stream>>>(W1, W2, W3, W4, ws);
    k_absmax<<<2048, 256, 0, stream>>>((const float4*)x, slots, (in_sizes[0] + 3) / 4);
    k_stage<1><<<blocks, 256, 0, stream>>>(x, b1, b2, b3, b4, ws, slots, out);
    k_stage<2><<<blocks, 256, 0, stream>>>(x, b1, b2, b3, b4, ws, slots, out);
    k_stage<3><<<blocks, 256, 0, stream>>>(x, b1, b2, b3, b4, ws, slots, out);
    k_stage<4><<<blocks, 256, 0, stream>>>(x, b1, b2, b3, b4, ws, slots, out);
}